// Round 2
// baseline (6843.522 us; speedup 1.0000x reference)
//
#include <hip/hip_runtime.h>
#include <math.h>

// TrittentionCube: B=16, S=512, HID=2048, H=4, D=512 (S==D)
// Round 1: chunked fp32 pipeline. Round 0 crashed with a GPU memory fault —
// workspace plan was 448 MiB, likely exceeding ws_size. Now chunked over B
// (8 chunks x 2 batches): peak ws = 56 MiB.
//   per chunk:
//     phase 1: q,k,v,ck,cv = heads(hs_chunk @ W^T + b)   (NT gemm, scatter)
//     phase 2: s1 = q @ k^T          per (b,h)           (NT gemm, z=8)
//     phase 3: s2 = s1 @ ck^T * SCALE                    (NT gemm, z=8)
//     phase 4: probs = softmax(s2) in-place
//     phase 5: ctx1 = probs @ v                          (NN gemm, z=8)
//     phase 6: out  = merge_heads(ctx1 @ cv)             (NN gemm, fused store)

#define BM 64
#define BN 64
#define BK 16

#define CHUNK_B 2                    // batches per chunk
#define NCHUNK  (16 / CHUNK_B)       // 8 chunks
#define CBH     (CHUNK_B * 4)        // bh batches per chunk = 8

static constexpr float SCALE = 0.04419417382415922f;  // 1/sqrt(512)

__device__ __forceinline__ void store_result(
    float* __restrict__ C, long long sC, int z, int ldc, int mode,
    int m, int n, float val)
{
    if (mode == 0) {
        // plain row-major per batch
        C[(long long)z * sC + (long long)m * ldc + n] = val;
    } else if (mode == 1) {
        // projection scatter: rows m over CHUNK_B*512, cols n over HID=2048
        // -> chunk-local [CHUNK_B,H,S,D]
        int b = m >> 9, s = m & 511, h = n >> 9, d = n & 511;
        C[((long long)(b * 4 + h) * 512 + s) * 512 + d] = val;
    } else {
        // head merge: z = local bh, out pre-offset to chunk base;
        // out[b_local, m, h*512+n]
        int b = z >> 2, h = z & 3;
        C[((long long)(b * 512 + m)) * 2048 + h * 512 + n] = val;
    }
}

// C[m,n] = alpha * sum_k A[m,k]*B[n,k] (+bias[n]); A:[M,K] ld=K, B:[N,K] ld=K
__global__ __launch_bounds__(256)
void gemm_nt(const float* __restrict__ A, const float* __restrict__ B,
             const float* __restrict__ bias, float* __restrict__ C,
             int K, int ldc, long long sA, long long sB, long long sC,
             float alpha, int mode)
{
    __shared__ float As[BK][BM + 4];
    __shared__ float Bs[BK][BN + 4];
    const int t  = threadIdx.x;
    const int bm = blockIdx.y * BM;
    const int bn = blockIdx.x * BN;
    const int z  = blockIdx.z;
    const float* Ab = A + (long long)z * sA;
    const float* Bb = B + (long long)z * sB;

    const int lm = t >> 2;          // 0..63 : tile row
    const int lk = (t & 3) << 2;    // 0,4,8,12 : k quad
    const int ty = t >> 4;          // 0..15
    const int tx = t & 15;          // 0..15

    float acc[4][4] = {};

    for (int k0 = 0; k0 < K; k0 += BK) {
        float4 av = *(const float4*)(Ab + (long long)(bm + lm) * K + k0 + lk);
        float4 bv = *(const float4*)(Bb + (long long)(bn + lm) * K + k0 + lk);
        As[lk + 0][lm] = av.x; As[lk + 1][lm] = av.y;
        As[lk + 2][lm] = av.z; As[lk + 3][lm] = av.w;
        Bs[lk + 0][lm] = bv.x; Bs[lk + 1][lm] = bv.y;
        Bs[lk + 2][lm] = bv.z; Bs[lk + 3][lm] = bv.w;
        __syncthreads();
#pragma unroll
        for (int k = 0; k < BK; ++k) {
            float4 a = *(const float4*)&As[k][ty << 2];
            float4 b = *(const float4*)&Bs[k][tx << 2];
            float ar[4] = {a.x, a.y, a.z, a.w};
            float br[4] = {b.x, b.y, b.z, b.w};
#pragma unroll
            for (int i = 0; i < 4; ++i)
#pragma unroll
                for (int j = 0; j < 4; ++j)
                    acc[i][j] += ar[i] * br[j];
        }
        __syncthreads();
    }

#pragma unroll
    for (int i = 0; i < 4; ++i) {
        int m = bm + (ty << 2) + i;
#pragma unroll
        for (int j = 0; j < 4; ++j) {
            int n = bn + (tx << 2) + j;
            float val = acc[i][j] * alpha;
            if (bias) val += bias[n];
            store_result(C, sC, z, ldc, mode, m, n, val);
        }
    }
}

// C[m,n] = sum_k A[m,k]*B[k,n]; A:[M,K] ld=K, B:[K,N] ld=ldb
__global__ __launch_bounds__(256)
void gemm_nn(const float* __restrict__ A, const float* __restrict__ B,
             float* __restrict__ C,
             int K, int ldb, int ldc, long long sA, long long sB, long long sC,
             int mode)
{
    __shared__ float As[BK][BM + 4];
    __shared__ float Bs[BK][BN + 4];
    const int t  = threadIdx.x;
    const int bm = blockIdx.y * BM;
    const int bn = blockIdx.x * BN;
    const int z  = blockIdx.z;
    const float* Ab = A + (long long)z * sA;
    const float* Bb = B + (long long)z * sB;

    const int lm = t >> 2;          // 0..63
    const int lk = (t & 3) << 2;    // 0,4,8,12
    const int kr = t >> 4;          // 0..15  (B tile k-row)
    const int nq = (t & 15) << 2;   // 0..60  (B tile n quad)
    const int ty = t >> 4;
    const int tx = t & 15;

    float acc[4][4] = {};

    for (int k0 = 0; k0 < K; k0 += BK) {
        float4 av = *(const float4*)(Ab + (long long)(bm + lm) * K + k0 + lk);
        float4 bv = *(const float4*)(Bb + (long long)(k0 + kr) * ldb + bn + nq);
        As[lk + 0][lm] = av.x; As[lk + 1][lm] = av.y;
        As[lk + 2][lm] = av.z; As[lk + 3][lm] = av.w;
        *(float4*)&Bs[kr][nq] = bv;
        __syncthreads();
#pragma unroll
        for (int k = 0; k < BK; ++k) {
            float4 a = *(const float4*)&As[k][ty << 2];
            float4 b = *(const float4*)&Bs[k][tx << 2];
            float ar[4] = {a.x, a.y, a.z, a.w};
            float br[4] = {b.x, b.y, b.z, b.w};
#pragma unroll
            for (int i = 0; i < 4; ++i)
#pragma unroll
                for (int j = 0; j < 4; ++j)
                    acc[i][j] += ar[i] * br[j];
        }
        __syncthreads();
    }

#pragma unroll
    for (int i = 0; i < 4; ++i) {
        int m = bm + (ty << 2) + i;
#pragma unroll
        for (int j = 0; j < 4; ++j) {
            int n = bn + (tx << 2) + j;
            store_result(C, sC, z, ldc, mode, m, n, acc[i][j]);
        }
    }
}

// in-place softmax over rows of X: [R, 512], one block (256 thr) per row
__global__ __launch_bounds__(256)
void softmax_rows(float* __restrict__ X)
{
    __shared__ float sm[4];
    __shared__ float ss[4];
    const int t = threadIdx.x;
    float* x = X + (long long)blockIdx.x * 512;

    float v0 = x[t];
    float v1 = x[t + 256];

    float m = fmaxf(v0, v1);
#pragma unroll
    for (int o = 32; o > 0; o >>= 1) m = fmaxf(m, __shfl_xor(m, o));
    if ((t & 63) == 0) sm[t >> 6] = m;
    __syncthreads();
    float mAll = fmaxf(fmaxf(sm[0], sm[1]), fmaxf(sm[2], sm[3]));

    float e0 = __expf(v0 - mAll);
    float e1 = __expf(v1 - mAll);
    float s = e0 + e1;
#pragma unroll
    for (int o = 32; o > 0; o >>= 1) s += __shfl_xor(s, o);
    if ((t & 63) == 0) ss[t >> 6] = s;
    __syncthreads();
    float inv = 1.0f / (ss[0] + ss[1] + ss[2] + ss[3]);

    x[t]       = e0 * inv;
    x[t + 256] = e1 * inv;
}

extern "C" void kernel_launch(void* const* d_in, const int* in_sizes, int n_in,
                              void* d_out, int out_size, void* d_ws, size_t ws_size,
                              hipStream_t stream)
{
    const float* hs = (const float*)d_in[0];
    const float* W[5]  = {(const float*)d_in[1], (const float*)d_in[3],
                          (const float*)d_in[5], (const float*)d_in[7],
                          (const float*)d_in[9]};
    const float* bv[5] = {(const float*)d_in[2], (const float*)d_in[4],
                          (const float*)d_in[6], (const float*)d_in[8],
                          (const float*)d_in[10]};

    // per-chunk buffers: [CHUNK_B, H, 512, 512] = 2*4*512*512 = 2M floats (8 MiB)
    const long long CHSZ = (long long)CHUNK_B * 4 * 512 * 512;
    float* ws = (float*)d_ws;
    float* q  = ws + 0 * CHSZ;
    float* kk = ws + 1 * CHSZ;
    float* v  = ws + 2 * CHSZ;
    float* ck = ws + 3 * CHSZ;
    float* cv = ws + 4 * CHSZ;
    float* s1 = ws + 5 * CHSZ;   // reused for ctx1
    float* s2 = ws + 6 * CHSZ;   // probs (in-place softmax)
    // total ws use: 7 * 8 MiB = 56 MiB

    float* out = (float*)d_out;
    dim3 blk(256);
    const long long SB = 512LL * 512;  // per-(b,h) matrix stride
    const int MROW = CHUNK_B * 512;    // 1024 rows per projection chunk

    float* dsts[5] = {q, kk, v, ck, cv};

    for (int c = 0; c < NCHUNK; ++c) {
        const float* hs_c  = hs  + (long long)c * MROW * 2048;
        float*       out_c = out + (long long)c * MROW * 2048;

        // phase 1: projections [1024,2048]@[2048,2048]^T, scatter to chunk [b,h,s,d]
        for (int p = 0; p < 5; ++p) {
            gemm_nt<<<dim3(2048 / BN, MROW / BM, 1), blk, 0, stream>>>(
                hs_c, W[p], bv[p], dsts[p],
                /*K=*/2048, /*ldc=*/0, /*sA=*/0, /*sB=*/0, /*sC=*/0,
                /*alpha=*/1.0f, /*mode=*/1);
        }

        // phase 2: s1 = q @ k^T, batched over CBH (b,h)
        gemm_nt<<<dim3(8, 8, CBH), blk, 0, stream>>>(
            q, kk, nullptr, s1, 512, 512, SB, SB, SB, 1.0f, 0);

        // phase 3: s2 = s1 @ ck^T * SCALE
        gemm_nt<<<dim3(8, 8, CBH), blk, 0, stream>>>(
            s1, ck, nullptr, s2, 512, 512, SB, SB, SB, SCALE, 0);

        // phase 4: softmax over CBH*512 rows
        softmax_rows<<<dim3(CBH * 512), blk, 0, stream>>>(s2);

        // phase 5: ctx1 = probs @ v  (into s1's buffer)
        gemm_nn<<<dim3(8, 8, CBH), blk, 0, stream>>>(
            s2, v, s1, 512, 512, 512, SB, SB, SB, 0);

        // phase 6: out = merge_heads(ctx1 @ cv), chunk-offset output
        gemm_nn<<<dim3(8, 8, CBH), blk, 0, stream>>>(
            s1, cv, out_c, 512, 512, 0, SB, SB, 0, 2);
    }

    (void)in_sizes; (void)n_in; (void)out_size; (void)ws_size;
}

// Round 3
// 1057.650 us; speedup vs baseline: 6.4705x; 6.4705x over previous
//
#include <hip/hip_runtime.h>
#include <math.h>

// TrittentionCube: B=16, S=512, HID=2048, H=4, D=512 (S==D)
// Round 2: fp16 MFMA. Projections = 128x128-tile NT GEMM (16x16x32_f16).
// Chain fused per (b,h,64-row q-strip): S1=Q@K^T -> S2=S1@CK^T*scale ->
// softmax -> C1=P@V -> OUT=C1@CV, all NT via LDS transpose staging of V/CV,
// intermediates live in a 64x520 LDS buffer. ws-adaptive full/chunked paths.

typedef _Float16 f16;
typedef f16 f16x8 __attribute__((ext_vector_type(8)));
typedef float f32x4 __attribute__((ext_vector_type(4)));
typedef float f32x16 __attribute__((ext_vector_type(16)));

#define SB_STRIDE 520   // 64 rows, padded (16B-aligned rows, 4-way max conflicts)
#define BP_STRIDE 72    // 512 rows of 64 k-halfs + 8 pad
#define CHAIN_LDS ((64 * SB_STRIDE + 512 * BP_STRIDE) * 2)  // 140,288 B

static constexpr float SCALE = 0.04419417382415922f;  // 1/sqrt(512)

// ---------------------------------------------------------------- convert
__global__ __launch_bounds__(256) void conv_f32_f16(const float* __restrict__ src,
                                                    f16* __restrict__ dst, int n)
{
    int i = (blockIdx.x * 256 + threadIdx.x) * 8;
    if (i + 8 <= n) {
        float4 a = *(const float4*)(src + i);
        float4 b = *(const float4*)(src + i + 4);
        f16 o[8] = {(f16)a.x, (f16)a.y, (f16)a.z, (f16)a.w,
                    (f16)b.x, (f16)b.y, (f16)b.z, (f16)b.w};
        *(int4*)(dst + i) = *(int4*)o;
    }
}

// ---------------------------------------------------------------- projections
struct ProjPtrs {
    const f16* W[5];
    const float* bias[5];
    f16* dst[5];
};

// C[m,n] = sum_k A[m,k] * W[n,k] + bias[n], scattered to [bh][s][d] fp16.
// Block 128x128, BK=32, 4 waves in 2x2 of 64x64, 16x16x32_f16.
__global__ __launch_bounds__(256) void proj_f16(const f16* __restrict__ A, ProjPtrs P)
{
    __shared__ f16 As[128][40];
    __shared__ f16 Bs[128][40];
    const int z = blockIdx.z;
    const f16* __restrict__ W = P.W[z];
    const float* __restrict__ bias = P.bias[z];
    f16* __restrict__ dst = P.dst[z];

    const int t    = threadIdx.x;
    const int lane = t & 63;
    const int wave = t >> 6;
    const int wm = (wave >> 1) * 64, wn = (wave & 1) * 64;
    const int bm = blockIdx.y * 128, bn = blockIdx.x * 128;

    const int srow = t >> 1;            // 0..127 staging row
    const int skc  = (t & 1) * 16;      // half-row (16 halfs)

    const int lm = lane & 15;           // frag row
    const int lk = (lane >> 4) * 8;     // frag k-offset

    f32x4 acc[4][4];
#pragma unroll
    for (int i = 0; i < 4; ++i)
#pragma unroll
        for (int j = 0; j < 4; ++j)
#pragma unroll
            for (int r = 0; r < 4; ++r) acc[i][j][r] = 0.f;

    for (int k0 = 0; k0 < 2048; k0 += 32) {
        int4 a0 = *(const int4*)(A + (size_t)(bm + srow) * 2048 + k0 + skc);
        int4 a1 = *(const int4*)(A + (size_t)(bm + srow) * 2048 + k0 + skc + 8);
        int4 b0 = *(const int4*)(W + (size_t)(bn + srow) * 2048 + k0 + skc);
        int4 b1 = *(const int4*)(W + (size_t)(bn + srow) * 2048 + k0 + skc + 8);
        __syncthreads();
        *(int4*)&As[srow][skc]     = a0;
        *(int4*)&As[srow][skc + 8] = a1;
        *(int4*)&Bs[srow][skc]     = b0;
        *(int4*)&Bs[srow][skc + 8] = b1;
        __syncthreads();
        f16x8 af[4], bf[4];
#pragma unroll
        for (int mt = 0; mt < 4; ++mt) af[mt] = *(const f16x8*)&As[wm + mt * 16 + lm][lk];
#pragma unroll
        for (int nt = 0; nt < 4; ++nt) bf[nt] = *(const f16x8*)&Bs[wn + nt * 16 + lm][lk];
#pragma unroll
        for (int mt = 0; mt < 4; ++mt)
#pragma unroll
            for (int nt = 0; nt < 4; ++nt)
                acc[mt][nt] = __builtin_amdgcn_mfma_f32_16x16x32_f16(af[mt], bf[nt], acc[mt][nt], 0, 0, 0);
    }

    // epilogue: C/D mapping col=lane&15, row=(lane>>4)*4+reg
#pragma unroll
    for (int nt = 0; nt < 4; ++nt) {
        int n = bn + wn + nt * 16 + lm;
        float bb = bias[n];
        int h = n >> 9, d = n & 511;
#pragma unroll
        for (int mt = 0; mt < 4; ++mt) {
            int mbase = bm + wm + mt * 16 + (lane >> 4) * 4;
#pragma unroll
            for (int r = 0; r < 4; ++r) {
                int m = mbase + r;
                int b = m >> 9, s = m & 511;
                dst[(((size_t)(b * 4 + h)) * 512 + s) * 512 + d] = (f16)(acc[mt][nt][r] + bb);
            }
        }
    }
}

// ---------------------------------------------------------------- fused chain
// One stage: acc[64 x 512] = Sbuf(A) @ Bsrc^T, Bsrc either [n][k] ([s][d] order,
// NT-ready) or [k][n] (transposed-staged). 32x32x16_f16; wave w owns n-strip 128w.
__device__ __forceinline__ void stage_compute(
    const f16* __restrict__ Bsrc, int transposed,
    f16* __restrict__ Sb, f16* __restrict__ Bp, int t, f32x16 acc[2][4])
{
    const int lane = t & 63;
    const int wn   = (t >> 6) * 128;
    const int l31  = lane & 31;
    const int l5   = (lane >> 5) * 8;

#pragma unroll
    for (int mt = 0; mt < 2; ++mt)
#pragma unroll
        for (int nt = 0; nt < 4; ++nt)
#pragma unroll
            for (int r = 0; r < 16; ++r) acc[mt][nt][r] = 0.f;

    for (int p = 0; p < 8; ++p) {
        const int k0 = p * 64;
        __syncthreads();  // protect prior-panel reads / prior Sbuf epilogue
        if (!transposed) {
            // Bpan[n][0..64) <- Bsrc[n][k0..k0+64)
            for (int i = t; i < 4096; i += 256) {
                int n = i >> 3, c = (i & 7) * 8;
                *(int4*)(Bp + (size_t)n * BP_STRIDE + c) =
                    *(const int4*)(Bsrc + (size_t)n * 512 + k0 + c);
            }
        } else {
            // Bpan[d][m-k0] <- Bsrc[m][d] transposed (b64-packed writes)
            int g = t & 15;              // 4 source rows k0+g*4 ..
            int dbase = (t >> 4) * 32;   // 32 d-columns per thread
            for (int dd = 0; dd < 32; dd += 8) {
                int4 r0 = *(const int4*)(Bsrc + (size_t)(k0 + g * 4 + 0) * 512 + dbase + dd);
                int4 r1 = *(const int4*)(Bsrc + (size_t)(k0 + g * 4 + 1) * 512 + dbase + dd);
                int4 r2 = *(const int4*)(Bsrc + (size_t)(k0 + g * 4 + 2) * 512 + dbase + dd);
                int4 r3 = *(const int4*)(Bsrc + (size_t)(k0 + g * 4 + 3) * 512 + dbase + dd);
                const f16* h0 = (const f16*)&r0;
                const f16* h1 = (const f16*)&r1;
                const f16* h2 = (const f16*)&r2;
                const f16* h3 = (const f16*)&r3;
#pragma unroll
                for (int j = 0; j < 8; ++j) {
                    f16 pk[4] = {h0[j], h1[j], h2[j], h3[j]};
                    *(float2*)(Bp + (size_t)(dbase + dd + j) * BP_STRIDE + g * 4) = *(float2*)pk;
                }
            }
        }
        __syncthreads();
#pragma unroll
        for (int dk = 0; dk < 64; dk += 16) {
            f16x8 af[2], bf[4];
#pragma unroll
            for (int mt = 0; mt < 2; ++mt)
                af[mt] = *(const f16x8*)(Sb + (size_t)(mt * 32 + l31) * SB_STRIDE + k0 + dk + l5);
#pragma unroll
            for (int nt = 0; nt < 4; ++nt)
                bf[nt] = *(const f16x8*)(Bp + (size_t)(wn + nt * 32 + l31) * BP_STRIDE + dk + l5);
#pragma unroll
            for (int mt = 0; mt < 2; ++mt)
#pragma unroll
                for (int nt = 0; nt < 4; ++nt)
                    acc[mt][nt] = __builtin_amdgcn_mfma_f32_32x32x16_f16(af[mt], bf[nt], acc[mt][nt], 0, 0, 0);
        }
    }
    __syncthreads();  // reads of Sb done -> caller may overwrite Sb
}

// C/D mapping 32x32: col=lane&31, row=(reg&3)+8*(reg>>2)+4*(lane>>5)
__device__ __forceinline__ void emit_to_S(f16* __restrict__ Sb, const f32x16 acc[2][4],
                                          int t, float scale)
{
    const int lane = t & 63;
    const int wn = (t >> 6) * 128;
#pragma unroll
    for (int mt = 0; mt < 2; ++mt)
#pragma unroll
        for (int nt = 0; nt < 4; ++nt) {
            int col = wn + nt * 32 + (lane & 31);
#pragma unroll
            for (int r = 0; r < 16; ++r) {
                int row = mt * 32 + (r & 3) + 8 * (r >> 2) + 4 * (lane >> 5);
                Sb[(size_t)row * SB_STRIDE + col] = (f16)(acc[mt][nt][r] * scale);
            }
        }
}

__global__ __launch_bounds__(256) void chain_f16(
    const f16* __restrict__ q16, const f16* __restrict__ k16,
    const f16* __restrict__ ck16, const f16* __restrict__ v16,
    const f16* __restrict__ cv16, float* __restrict__ out)
{
    extern __shared__ f16 smem[];
    f16* Sb = smem;                       // [64][SB_STRIDE]
    f16* Bp = smem + 64 * SB_STRIDE;      // [512][BP_STRIDE]
    const int t = threadIdx.x;
    const int bh = blockIdx.x >> 3;
    const int q0 = (blockIdx.x & 7) * 64;
    const size_t SB = 512 * 512;

    // stage Q[q0..q0+64) into Sbuf
    const f16* Q = q16 + bh * SB;
    for (int i = t; i < 4096; i += 256) {
        int row = i >> 6, c = (i & 63) * 8;
        *(int4*)(Sb + (size_t)row * SB_STRIDE + c) =
            *(const int4*)(Q + (size_t)(q0 + row) * 512 + c);
    }
    // stage_compute's leading __syncthreads covers the staging hazard

    f32x16 acc[2][4];

    // S1 = Q @ K^T
    stage_compute(k16 + bh * SB, 0, Sb, Bp, t, acc);
    emit_to_S(Sb, acc, t, 1.0f);

    // S2 = S1 @ CK^T * SCALE
    stage_compute(ck16 + bh * SB, 0, Sb, Bp, t, acc);
    emit_to_S(Sb, acc, t, SCALE);
    __syncthreads();

    // softmax rows (wave w -> rows 16w..16w+16)
    {
        const int lane = t & 63;
        const int wave = t >> 6;
        for (int rr = 0; rr < 16; ++rr) {
            int r = wave * 16 + rr;
            f16x8 xv = *(const f16x8*)(Sb + (size_t)r * SB_STRIDE + lane * 8);
            float x[8];
            float mx = -1e30f;
#pragma unroll
            for (int j = 0; j < 8; ++j) { x[j] = (float)xv[j]; mx = fmaxf(mx, x[j]); }
#pragma unroll
            for (int o = 32; o > 0; o >>= 1) mx = fmaxf(mx, __shfl_xor(mx, o));
            float s = 0.f;
#pragma unroll
            for (int j = 0; j < 8; ++j) { x[j] = __expf(x[j] - mx); s += x[j]; }
#pragma unroll
            for (int o = 32; o > 0; o >>= 1) s += __shfl_xor(s, o);
            float inv = 1.0f / s;
            f16x8 ov;
#pragma unroll
            for (int j = 0; j < 8; ++j) ov[j] = (f16)(x[j] * inv);
            *(f16x8*)(Sb + (size_t)r * SB_STRIDE + lane * 8) = ov;
        }
    }
    // stage_compute's leading barriers cover softmax-write -> A-frag-read

    // C1 = P @ V   (V staged transposed)
    stage_compute(v16 + bh * SB, 1, Sb, Bp, t, acc);
    emit_to_S(Sb, acc, t, 1.0f);

    // OUT = C1 @ CV (CV staged transposed), merge-heads store f32
    stage_compute(cv16 + bh * SB, 1, Sb, Bp, t, acc);
    {
        const int lane = t & 63;
        const int wn = (t >> 6) * 128;
        int b = bh >> 2, h = bh & 3;
#pragma unroll
        for (int mt = 0; mt < 2; ++mt)
#pragma unroll
            for (int nt = 0; nt < 4; ++nt) {
                int col = h * 512 + wn + nt * 32 + (lane & 31);
#pragma unroll
                for (int r = 0; r < 16; ++r) {
                    int row = q0 + mt * 32 + (r & 3) + 8 * (r >> 2) + 4 * (lane >> 5);
                    out[((size_t)b * 512 + row) * 2048 + col] = acc[mt][nt][r];
                }
            }
    }
}

// ---------------------------------------------------------------- host
extern "C" void kernel_launch(void* const* d_in, const int* in_sizes, int n_in,
                              void* d_out, int out_size, void* d_ws, size_t ws_size,
                              hipStream_t stream)
{
    const float* hs = (const float*)d_in[0];
    const float* Wf[5] = {(const float*)d_in[1], (const float*)d_in[3],
                          (const float*)d_in[5], (const float*)d_in[7],
                          (const float*)d_in[9]};
    const float* bf[5] = {(const float*)d_in[2], (const float*)d_in[4],
                          (const float*)d_in[6], (const float*)d_in[8],
                          (const float*)d_in[10]};
    float* out = (float*)d_out;

    // allow 140 KB dynamic LDS for the chain kernel (non-stream call: capture-safe)
    hipFuncSetAttribute((const void*)chain_f16,
                        hipFuncAttributeMaxDynamicSharedMemorySize, CHAIN_LDS);

    f16* ws = (f16*)d_ws;
    const size_t WELEM = 2048ULL * 2048;      // 4,194,304
    const size_t FULLACT = 64ULL * 512 * 512; // 16,777,216

    f16* W16[5];
    for (int i = 0; i < 5; ++i) W16[i] = ws + i * WELEM;
    f16* after_w = ws + 5 * WELEM;

    for (int i = 0; i < 5; ++i)
        conv_f32_f16<<<dim3(WELEM / 2048), 256, 0, stream>>>(Wf[i], W16[i], (int)WELEM);

    size_t full_need = (5 * WELEM + FULLACT + 5 * FULLACT) * sizeof(f16);  // 243,269,632
    if (ws_size >= full_need) {
        // ---------------- full path: 8 launches ----------------
        f16* hs16 = after_w;
        f16* act[5];
        for (int i = 0; i < 5; ++i) act[i] = after_w + FULLACT + i * FULLACT;

        conv_f32_f16<<<dim3(FULLACT / 2048), 256, 0, stream>>>(hs, hs16, (int)FULLACT);

        ProjPtrs P;
        for (int i = 0; i < 5; ++i) { P.W[i] = W16[i]; P.bias[i] = bf[i]; P.dst[i] = act[i]; }
        proj_f16<<<dim3(16, 64, 5), 256, 0, stream>>>(hs16, P);

        // act order: q,k,v,ck,cv -> chain(q,k,ck,v,cv)
        chain_f16<<<dim3(512), 256, CHAIN_LDS, stream>>>(
            act[0], act[1], act[3], act[2], act[4], out);
    } else {
        // ---------------- chunked path (54.5 MB ws) ----------------
        const size_t CHROW = 1048576ULL;      // 512*2048 elems per batch
        const size_t CHACT = 4ULL * 512 * 512;
        f16* hs16c = after_w;
        f16* act[5];
        for (int i = 0; i < 5; ++i) act[i] = after_w + CHROW + i * CHACT;

        ProjPtrs P;
        for (int i = 0; i < 5; ++i) { P.W[i] = W16[i]; P.bias[i] = bf[i]; P.dst[i] = act[i]; }

        for (int c = 0; c < 16; ++c) {
            conv_f32_f16<<<dim3(CHROW / 2048), 256, 0, stream>>>(
                hs + c * CHROW, hs16c, (int)CHROW);
            proj_f16<<<dim3(16, 4, 5), 256, 0, stream>>>(hs16c, P);
            chain_f16<<<dim3(32), 256, CHAIN_LDS, stream>>>(
                act[0], act[1], act[3], act[2], act[4], out + c * CHROW);
        }
    }

    (void)in_sizes; (void)n_in; (void)out_size;
}

// Round 4
// 1020.374 us; speedup vs baseline: 6.7069x; 1.0365x over previous
//
#include <hip/hip_runtime.h>
#include <math.h>

// TrittentionCube: B=16, S=512, HID=2048, H=4, D=512 (S==D)
// Round 4: proj_f16 -> m97-style global_load_lds staging with fragment-order
// LDS blocks (lane-linear stage AND frag reads). chain_f16 -> 512 threads
// (8 waves, 2/SIMD) + global_load_lds for the NT-panel stages.

typedef _Float16 f16;
typedef f16 f16x8 __attribute__((ext_vector_type(8)));
typedef float f32x4 __attribute__((ext_vector_type(4)));
typedef float f32x16 __attribute__((ext_vector_type(16)));

#define SB_STRIDE 520   // chain S-buffer row stride (halfs), 16B-aligned rows
#define BP_STRIDE 72    // chain transposed-panel stride (halfs)
#define CHAIN_LDS ((64 * SB_STRIDE + 512 * BP_STRIDE) * 2)  // 140,288 B

static constexpr float SCALE = 0.04419417382415922f;  // 1/sqrt(512)

// async global->LDS, 16B per lane; LDS dest = uniform base + lane*16
__device__ __forceinline__ void gl_lds16(const f16* g, f16* l)
{
    __builtin_amdgcn_global_load_lds(
        (const __attribute__((address_space(1))) void*)g,
        (__attribute__((address_space(3))) void*)l, 16, 0, 0);
}

// ---------------------------------------------------------------- convert
__global__ __launch_bounds__(256) void conv_f32_f16(const float* __restrict__ src,
                                                    f16* __restrict__ dst, int n)
{
    int i = (blockIdx.x * 256 + threadIdx.x) * 8;
    if (i + 8 <= n) {
        float4 a = *(const float4*)(src + i);
        float4 b = *(const float4*)(src + i + 4);
        f16 o[8] = {(f16)a.x, (f16)a.y, (f16)a.z, (f16)a.w,
                    (f16)b.x, (f16)b.y, (f16)b.z, (f16)b.w};
        *(int4*)(dst + i) = *(int4*)o;
    }
}

// ---------------------------------------------------------------- projections
struct ProjPtrs {
    const f16* W[5];
    const float* bias[5];
    f16* dst[5];
};

// C[m,n] = sum_k A[m,k] * W[n,k] + bias[n], scattered to [bh][s][d] fp16.
// Block 128x128, BK=32, 4 waves in 2x2 of 64x64, 16x16x32_f16.
// LDS tile layout (fragment order): [8 mblk][4 kgrp][16 row][8 halfs];
// both staging (global_load_lds) and frag reads are lane-linear.
__global__ __launch_bounds__(256) void proj_f16(const f16* __restrict__ A, ProjPtrs P)
{
    __shared__ f16 AsF[4096];   // 8 KB
    __shared__ f16 BsF[4096];
    const int z = blockIdx.z;
    const f16* __restrict__ W = P.W[z];
    const float* __restrict__ bias = P.bias[z];
    f16* __restrict__ dst = P.dst[z];

    const int t    = threadIdx.x;
    const int lane = t & 63;
    const int wave = t >> 6;
    const int bm = blockIdx.y * 128, bn = blockIdx.x * 128;

    const int r15 = lane & 15;          // frag row / staging row
    const int kc  = (lane >> 4) * 8;    // frag k-offset (halfs)

    // staging source pointers: wave w stages m-blocks w*2, w*2+1 (A and B)
    const f16* aP0 = A + (size_t)(bm + (wave * 2 + 0) * 16 + r15) * 2048 + kc;
    const f16* aP1 = A + (size_t)(bm + (wave * 2 + 1) * 16 + r15) * 2048 + kc;
    const f16* bP0 = W + (size_t)(bn + (wave * 2 + 0) * 16 + r15) * 2048 + kc;
    const f16* bP1 = W + (size_t)(bn + (wave * 2 + 1) * 16 + r15) * 2048 + kc;
    f16* aL0 = AsF + (wave * 2 + 0) * 512;
    f16* aL1 = AsF + (wave * 2 + 1) * 512;
    f16* bL0 = BsF + (wave * 2 + 0) * 512;
    f16* bL1 = BsF + (wave * 2 + 1) * 512;

    const int wmB = (wave >> 1) * 4;    // wave's first m-block
    const int wnB = (wave & 1) * 4;     // wave's first n-block

    f32x4 acc[4][4];
#pragma unroll
    for (int i = 0; i < 4; ++i)
#pragma unroll
        for (int j = 0; j < 4; ++j)
#pragma unroll
            for (int r = 0; r < 4; ++r) acc[i][j][r] = 0.f;

    for (int k0 = 0; k0 < 2048; k0 += 32) {
        __syncthreads();                 // all frag reads of prev iter done
        gl_lds16(aP0 + k0, aL0);
        gl_lds16(aP1 + k0, aL1);
        gl_lds16(bP0 + k0, bL0);
        gl_lds16(bP1 + k0, bL1);
        __syncthreads();                 // vmcnt(0) drained before barrier

        f16x8 af[4], bf[4];
#pragma unroll
        for (int mt = 0; mt < 4; ++mt)
            af[mt] = *(const f16x8*)(AsF + (wmB + mt) * 512 + lane * 8);
#pragma unroll
        for (int nt = 0; nt < 4; ++nt)
            bf[nt] = *(const f16x8*)(BsF + (wnB + nt) * 512 + lane * 8);
#pragma unroll
        for (int mt = 0; mt < 4; ++mt)
#pragma unroll
            for (int nt = 0; nt < 4; ++nt)
                acc[mt][nt] = __builtin_amdgcn_mfma_f32_16x16x32_f16(af[mt], bf[nt], acc[mt][nt], 0, 0, 0);
    }

    // epilogue: C/D mapping col(n)=lane&15, row(m)=(lane>>4)*4+reg
    const int wm = (wave >> 1) * 64, wn = (wave & 1) * 64;
#pragma unroll
    for (int nt = 0; nt < 4; ++nt) {
        int n = bn + wn + nt * 16 + r15;
        float bb = bias[n];
        int h = n >> 9, d = n & 511;
#pragma unroll
        for (int mt = 0; mt < 4; ++mt) {
            int mbase = bm + wm + mt * 16 + (lane >> 4) * 4;
#pragma unroll
            for (int r = 0; r < 4; ++r) {
                int m = mbase + r;
                int b = m >> 9, s = m & 511;
                dst[(((size_t)(b * 4 + h)) * 512 + s) * 512 + d] = (f16)(acc[mt][nt][r] + bb);
            }
        }
    }
}

// ---------------------------------------------------------------- fused chain
// 512 threads, 8 waves; wave w owns 64-col n-strip. acc[2][2] (64x512 tile).
// Non-transposed panels: global_load_lds into block layout
//   [16 nb][8 kg2][32 n][8 halfs]  (frag reads lane-linear)
// Transposed panels (V,CV): VALU transpose into padded [512][BP_STRIDE].
__device__ __forceinline__ void stage_compute(
    const f16* __restrict__ Bsrc, int transposed,
    f16* __restrict__ Sb, f16* __restrict__ Bp, int t, f32x16 acc[2][2])
{
    const int lane = t & 63;
    const int wave = t >> 6;
    const int wn   = wave * 64;
    const int l31  = lane & 31;
    const int l5   = (lane >> 5) * 8;

#pragma unroll
    for (int mt = 0; mt < 2; ++mt)
#pragma unroll
        for (int nt = 0; nt < 2; ++nt)
#pragma unroll
            for (int r = 0; r < 16; ++r) acc[mt][nt][r] = 0.f;

    for (int p = 0; p < 8; ++p) {
        const int k0 = p * 64;
        __syncthreads();  // prior-panel reads / prior Sbuf writes complete
        if (!transposed) {
            // wave w stages nb = 2w, 2w+1; ks = 0..3 (16 k each)
#pragma unroll
            for (int it = 0; it < 8; ++it) {
                int nb = wave * 2 + (it & 1);
                int ks = it >> 1;
                gl_lds16(Bsrc + (size_t)(nb * 32 + l31) * 512 + k0 + ks * 16 + l5,
                         Bp + nb * 2048 + ks * 512);
            }
        } else {
            // Bpan[d][m-k0] <- Bsrc[m][d] transposed, padded stride
            int g = t & 15;              // source rows k0+g*4 .. +3
            int dbase = (t >> 4) * 16;   // 32 groups x 16 d-cols
            for (int dd = 0; dd < 16; dd += 8) {
                int4 r0 = *(const int4*)(Bsrc + (size_t)(k0 + g * 4 + 0) * 512 + dbase + dd);
                int4 r1 = *(const int4*)(Bsrc + (size_t)(k0 + g * 4 + 1) * 512 + dbase + dd);
                int4 r2 = *(const int4*)(Bsrc + (size_t)(k0 + g * 4 + 2) * 512 + dbase + dd);
                int4 r3 = *(const int4*)(Bsrc + (size_t)(k0 + g * 4 + 3) * 512 + dbase + dd);
                const f16* h0 = (const f16*)&r0;
                const f16* h1 = (const f16*)&r1;
                const f16* h2 = (const f16*)&r2;
                const f16* h3 = (const f16*)&r3;
#pragma unroll
                for (int j = 0; j < 8; ++j) {
                    f16 pk[4] = {h0[j], h1[j], h2[j], h3[j]};
                    *(float2*)(Bp + (size_t)(dbase + dd + j) * BP_STRIDE + g * 4) = *(float2*)pk;
                }
            }
        }
        __syncthreads();
#pragma unroll
        for (int dk = 0; dk < 64; dk += 16) {
            f16x8 af[2], bf[2];
#pragma unroll
            for (int mt = 0; mt < 2; ++mt)
                af[mt] = *(const f16x8*)(Sb + (size_t)(mt * 32 + l31) * SB_STRIDE + k0 + dk + l5);
            if (!transposed) {
#pragma unroll
                for (int nt = 0; nt < 2; ++nt)
                    bf[nt] = *(const f16x8*)(Bp + (wave * 2 + nt) * 2048 + (dk >> 3) * 256 + lane * 8);
            } else {
#pragma unroll
                for (int nt = 0; nt < 2; ++nt)
                    bf[nt] = *(const f16x8*)(Bp + (size_t)(wn + nt * 32 + l31) * BP_STRIDE + dk + l5);
            }
#pragma unroll
            for (int mt = 0; mt < 2; ++mt)
#pragma unroll
                for (int nt = 0; nt < 2; ++nt)
                    acc[mt][nt] = __builtin_amdgcn_mfma_f32_32x32x16_f16(af[mt], bf[nt], acc[mt][nt], 0, 0, 0);
        }
    }
    __syncthreads();  // reads of Sb done -> caller may overwrite Sb
}

// C/D mapping 32x32: col=lane&31, row=(reg&3)+8*(reg>>2)+4*(lane>>5)
__device__ __forceinline__ void emit_to_S(f16* __restrict__ Sb, const f32x16 acc[2][2],
                                          int t, float scale)
{
    const int lane = t & 63;
    const int wn = (t >> 6) * 64;
#pragma unroll
    for (int mt = 0; mt < 2; ++mt)
#pragma unroll
        for (int nt = 0; nt < 2; ++nt) {
            int col = wn + nt * 32 + (lane & 31);
#pragma unroll
            for (int r = 0; r < 16; ++r) {
                int row = mt * 32 + (r & 3) + 8 * (r >> 2) + 4 * (lane >> 5);
                Sb[(size_t)row * SB_STRIDE + col] = (f16)(acc[mt][nt][r] * scale);
            }
        }
}

__global__ __launch_bounds__(512) void chain_f16(
    const f16* __restrict__ q16, const f16* __restrict__ k16,
    const f16* __restrict__ ck16, const f16* __restrict__ v16,
    const f16* __restrict__ cv16, float* __restrict__ out)
{
    extern __shared__ f16 smem[];
    f16* Sb = smem;                       // [64][SB_STRIDE]
    f16* Bp = smem + 64 * SB_STRIDE;      // [512][BP_STRIDE] / block layout
    const int t = threadIdx.x;
    const int bh = blockIdx.x >> 3;
    const int q0 = (blockIdx.x & 7) * 64;
    const size_t SB = 512 * 512;

    // stage Q[q0..q0+64) into Sbuf
    const f16* Q = q16 + bh * SB;
    for (int i = t; i < 4096; i += 512) {
        int row = i >> 6, c = (i & 63) * 8;
        *(int4*)(Sb + (size_t)row * SB_STRIDE + c) =
            *(const int4*)(Q + (size_t)(q0 + row) * 512 + c);
    }

    f32x16 acc[2][2];

    // S1 = Q @ K^T
    stage_compute(k16 + bh * SB, 0, Sb, Bp, t, acc);
    emit_to_S(Sb, acc, t, 1.0f);

    // S2 = S1 @ CK^T * SCALE
    stage_compute(ck16 + bh * SB, 0, Sb, Bp, t, acc);
    emit_to_S(Sb, acc, t, SCALE);
    __syncthreads();

    // softmax rows (wave w -> rows 8w..8w+8)
    {
        const int lane = t & 63;
        const int wave = t >> 6;
        for (int rr = 0; rr < 8; ++rr) {
            int r = wave * 8 + rr;
            f16x8 xv = *(const f16x8*)(Sb + (size_t)r * SB_STRIDE + lane * 8);
            float x[8];
            float mx = -1e30f;
#pragma unroll
            for (int j = 0; j < 8; ++j) { x[j] = (float)xv[j]; mx = fmaxf(mx, x[j]); }
#pragma unroll
            for (int o = 32; o > 0; o >>= 1) mx = fmaxf(mx, __shfl_xor(mx, o));
            float s = 0.f;
#pragma unroll
            for (int j = 0; j < 8; ++j) { x[j] = __expf(x[j] - mx); s += x[j]; }
#pragma unroll
            for (int o = 32; o > 0; o >>= 1) s += __shfl_xor(s, o);
            float inv = 1.0f / s;
            f16x8 ov;
#pragma unroll
            for (int j = 0; j < 8; ++j) ov[j] = (f16)(x[j] * inv);
            *(f16x8*)(Sb + (size_t)r * SB_STRIDE + lane * 8) = ov;
        }
    }

    // C1 = P @ V   (V staged transposed)
    stage_compute(v16 + bh * SB, 1, Sb, Bp, t, acc);
    emit_to_S(Sb, acc, t, 1.0f);

    // OUT = C1 @ CV (CV staged transposed), merge-heads store f32
    stage_compute(cv16 + bh * SB, 1, Sb, Bp, t, acc);
    {
        const int lane = t & 63;
        const int wn = (t >> 6) * 64;
        int b = bh >> 2, h = bh & 3;
#pragma unroll
        for (int mt = 0; mt < 2; ++mt)
#pragma unroll
            for (int nt = 0; nt < 2; ++nt) {
                int col = h * 512 + wn + nt * 32 + (lane & 31);
#pragma unroll
                for (int r = 0; r < 16; ++r) {
                    int row = q0 + mt * 32 + (r & 3) + 8 * (r >> 2) + 4 * (lane >> 5);
                    out[((size_t)b * 512 + row) * 2048 + col] = acc[mt][nt][r];
                }
            }
    }
}

// ---------------------------------------------------------------- host
extern "C" void kernel_launch(void* const* d_in, const int* in_sizes, int n_in,
                              void* d_out, int out_size, void* d_ws, size_t ws_size,
                              hipStream_t stream)
{
    const float* hs = (const float*)d_in[0];
    const float* Wf[5] = {(const float*)d_in[1], (const float*)d_in[3],
                          (const float*)d_in[5], (const float*)d_in[7],
                          (const float*)d_in[9]};
    const float* bf[5] = {(const float*)d_in[2], (const float*)d_in[4],
                          (const float*)d_in[6], (const float*)d_in[8],
                          (const float*)d_in[10]};
    float* out = (float*)d_out;

    hipFuncSetAttribute((const void*)chain_f16,
                        hipFuncAttributeMaxDynamicSharedMemorySize, CHAIN_LDS);

    f16* ws = (f16*)d_ws;
    const size_t WELEM = 2048ULL * 2048;      // 4,194,304
    const size_t FULLACT = 64ULL * 512 * 512; // 16,777,216

    f16* W16[5];
    for (int i = 0; i < 5; ++i) W16[i] = ws + i * WELEM;
    f16* after_w = ws + 5 * WELEM;

    for (int i = 0; i < 5; ++i)
        conv_f32_f16<<<dim3(WELEM / 2048), 256, 0, stream>>>(Wf[i], W16[i], (int)WELEM);

    size_t full_need = (5 * WELEM + FULLACT + 5 * FULLACT) * sizeof(f16);  // 243,269,632
    if (ws_size >= full_need) {
        // ---------------- full path ----------------
        f16* hs16 = after_w;
        f16* act[5];
        for (int i = 0; i < 5; ++i) act[i] = after_w + FULLACT + i * FULLACT;

        conv_f32_f16<<<dim3(FULLACT / 2048), 256, 0, stream>>>(hs, hs16, (int)FULLACT);

        ProjPtrs P;
        for (int i = 0; i < 5; ++i) { P.W[i] = W16[i]; P.bias[i] = bf[i]; P.dst[i] = act[i]; }
        proj_f16<<<dim3(16, 64, 5), 256, 0, stream>>>(hs16, P);

        // act order: q,k,v,ck,cv -> chain(q,k,ck,v,cv)
        chain_f16<<<dim3(512), 512, CHAIN_LDS, stream>>>(
            act[0], act[1], act[3], act[2], act[4], out);
    } else {
        // ---------------- chunked path (54.5 MB ws) ----------------
        const size_t CHROW = 1048576ULL;      // 512*2048 elems per batch
        const size_t CHACT = 4ULL * 512 * 512;
        f16* hs16c = after_w;
        f16* act[5];
        for (int i = 0; i < 5; ++i) act[i] = after_w + CHROW + i * CHACT;

        ProjPtrs P;
        for (int i = 0; i < 5; ++i) { P.W[i] = W16[i]; P.bias[i] = bf[i]; P.dst[i] = act[i]; }

        for (int c = 0; c < 16; ++c) {
            conv_f32_f16<<<dim3(CHROW / 2048), 256, 0, stream>>>(
                hs + c * CHROW, hs16c, (int)CHROW);
            proj_f16<<<dim3(16, 4, 5), 256, 0, stream>>>(hs16c, P);
            chain_f16<<<dim3(32), 512, CHAIN_LDS, stream>>>(
                act[0], act[1], act[3], act[2], act[4], out + c * CHROW);
        }
    }

    (void)in_sizes; (void)n_in; (void)out_size;
}

// Round 5
// 1005.675 us; speedup vs baseline: 6.8049x; 1.0146x over previous
//
#include <hip/hip_runtime.h>
#include <math.h>

// TrittentionCube: B=16, S=512, HID=2048, H=4, D=512 (S==D)
// Round 5: proj = reg-prefetch pipeline + fragment-order LDS (conflict-free
// b128 both directions). V/CV written pre-transposed [bh][d][s] so the fused
// chain runs all 4 stages through the NT global_load_lds path with a
// double-buffered 32KB B-panel.

typedef _Float16 f16;
typedef f16 f16x8 __attribute__((ext_vector_type(8)));
typedef float f32x4 __attribute__((ext_vector_type(4)));
typedef float f32x16 __attribute__((ext_vector_type(16)));

#define SB_STRIDE 520            // S-buffer row stride (halfs): 2-way bank alias = free
#define BP_HALF   16384          // 32 KB panel buffer (halfs)
#define CHAIN_LDS ((64 * SB_STRIDE + 2 * BP_HALF) * 2)   // 132,096 B

static constexpr float SCALE = 0.04419417382415922f;  // 1/sqrt(512)

// async global->LDS, 16B per lane; LDS dest = wave-uniform base + lane*16
__device__ __forceinline__ void gl_lds16(const f16* g, f16* l)
{
    __builtin_amdgcn_global_load_lds(
        (const __attribute__((address_space(1))) void*)g,
        (__attribute__((address_space(3))) void*)l, 16, 0, 0);
}

// ---------------------------------------------------------------- convert
__global__ __launch_bounds__(256) void conv_f32_f16(const float* __restrict__ src,
                                                    f16* __restrict__ dst, int n)
{
    int i = (blockIdx.x * 256 + threadIdx.x) * 8;
    if (i + 8 <= n) {
        float4 a = *(const float4*)(src + i);
        float4 b = *(const float4*)(src + i + 4);
        f16 o[8] = {(f16)a.x, (f16)a.y, (f16)a.z, (f16)a.w,
                    (f16)b.x, (f16)b.y, (f16)b.z, (f16)b.w};
        *(int4*)(dst + i) = *(int4*)o;
    }
}

// ---------------------------------------------------------------- projections
struct ProjPtrs {
    const f16* W[5];
    const float* bias[5];
    f16* dst[5];
};

// C[m,n] = sum_k A[m,k] * W[n,k] + bias[n]. Block 128x128, BK=32, 4 waves
// (2x2 of 64x64), 16x16x32_f16. LDS fragment-order: slot s (512 slots of 16B)
// = [mblk=s>>6][kgrp=(s>>4)&3][row=s&15][8 halfs]. Thread t stages slots t and
// t+256 via reg round-trip (ds_write_b128, lane-linear => conflict-free).
// z==2 (v) and z==4 (cv) are stored transposed [bh][d][s] for the chain.
__global__ __launch_bounds__(256) void proj_f16(const f16* __restrict__ A, ProjPtrs P)
{
    __shared__ f16 AsF[4096];   // 8 KB
    __shared__ f16 BsF[4096];
    const int z = blockIdx.z;
    const f16* __restrict__ W = P.W[z];
    const float* __restrict__ bias = P.bias[z];
    f16* __restrict__ dst = P.dst[z];
    const bool tr = (z == 2) || (z == 4);

    const int t    = threadIdx.x;
    const int lane = t & 63;
    const int wave = t >> 6;
    const int bm = blockIdx.y * 128, bn = blockIdx.x * 128;

    // staging source for slots t and t+256
    const int srow = (t >> 6) * 16 + (t & 15);   // row within 128-tile (mblk 0..3)
    const int skc  = ((t >> 4) & 3) * 8;         // k offset (halfs)
    const f16* aP0 = A + (size_t)(bm + srow) * 2048 + skc;
    const f16* aP1 = aP0 + (size_t)64 * 2048;    // mblk + 4
    const f16* bP0 = W + (size_t)(bn + srow) * 2048 + skc;
    const f16* bP1 = bP0 + (size_t)64 * 2048;

    const int wmB = (wave >> 1) * 4;    // wave's first m-block
    const int wnB = (wave & 1) * 4;     // wave's first n-block

    f32x4 acc[4][4];
#pragma unroll
    for (int i = 0; i < 4; ++i)
#pragma unroll
        for (int j = 0; j < 4; ++j)
#pragma unroll
            for (int r = 0; r < 4; ++r) acc[i][j][r] = 0.f;

    // prologue: tile 0 into regs
    int4 ra0 = *(const int4*)aP0;
    int4 ra1 = *(const int4*)aP1;
    int4 rb0 = *(const int4*)bP0;
    int4 rb1 = *(const int4*)bP1;

    for (int k0 = 0; k0 < 2048; k0 += 32) {
        __syncthreads();                 // all frag reads of prev tile done
        *(int4*)(AsF + t * 8)        = ra0;
        *(int4*)(AsF + t * 8 + 2048) = ra1;
        *(int4*)(BsF + t * 8)        = rb0;
        *(int4*)(BsF + t * 8 + 2048) = rb1;
        __syncthreads();                 // tile visible to all

        if (k0 + 32 < 2048) {            // prefetch tile k+1 (in flight all iter)
            ra0 = *(const int4*)(aP0 + k0 + 32);
            ra1 = *(const int4*)(aP1 + k0 + 32);
            rb0 = *(const int4*)(bP0 + k0 + 32);
            rb1 = *(const int4*)(bP1 + k0 + 32);
        }

        f16x8 af[4], bf[4];
#pragma unroll
        for (int mt = 0; mt < 4; ++mt)
            af[mt] = *(const f16x8*)(AsF + (wmB + mt) * 512 + lane * 8);
#pragma unroll
        for (int nt = 0; nt < 4; ++nt)
            bf[nt] = *(const f16x8*)(BsF + (wnB + nt) * 512 + lane * 8);
#pragma unroll
        for (int mt = 0; mt < 4; ++mt)
#pragma unroll
            for (int nt = 0; nt < 4; ++nt)
                acc[mt][nt] = __builtin_amdgcn_mfma_f32_16x16x32_f16(af[mt], bf[nt], acc[mt][nt], 0, 0, 0);
    }

    // epilogue: C/D mapping col(n)=lane&15, row(m)=(lane>>4)*4+reg
    const int wm = (wave >> 1) * 64, wn = (wave & 1) * 64;
#pragma unroll
    for (int nt = 0; nt < 4; ++nt) {
        int n = bn + wn + nt * 16 + (lane & 15);
        float bb = bias[n];
        int h = n >> 9, d = n & 511;
#pragma unroll
        for (int mt = 0; mt < 4; ++mt) {
            int mbase = bm + wm + mt * 16 + (lane >> 4) * 4;
            int b = mbase >> 9, s0 = mbase & 511;
            if (!tr) {
#pragma unroll
                for (int r = 0; r < 4; ++r)
                    dst[(((size_t)(b * 4 + h)) * 512 + s0 + r) * 512 + d] =
                        (f16)(acc[mt][nt][r] + bb);
            } else {
                f16 pk[4];
#pragma unroll
                for (int r = 0; r < 4; ++r) pk[r] = (f16)(acc[mt][nt][r] + bb);
                *(float2*)(dst + (((size_t)(b * 4 + h)) * 512 + d) * 512 + s0) =
                    *(float2*)pk;
            }
        }
    }
}

// ---------------------------------------------------------------- fused chain
// 512 threads, 8 waves; wave w owns 64-col n-strip, acc[2][2] (64x512 tile).
// acc = Sb(64xK=512) @ Bsrc^T, Bsrc row-major [n][k] (ld=512).
// B-panel (k=32) layout: [nb 16][ks 2][n 32][8 halfs], double-buffered,
// staged with global_load_lds; panel p+1 in flight during panel p compute.
__device__ __forceinline__ void stage_nt(
    const f16* __restrict__ Bsrc,
    f16* __restrict__ Sb, f16* __restrict__ Bp, int t, f32x16 acc[2][2])
{
    const int lane = t & 63;
    const int wave = t >> 6;
    const int l31  = lane & 31;
    const int l5   = (lane >> 5) * 8;

#pragma unroll
    for (int mt = 0; mt < 2; ++mt)
#pragma unroll
        for (int nt = 0; nt < 2; ++nt)
#pragma unroll
            for (int r = 0; r < 16; ++r) acc[mt][nt][r] = 0.f;

    // issue panel 0 -> buf0 (safe: prior reads of buf0 ended before caller's sync)
#pragma unroll
    for (int it = 0; it < 4; ++it) {
        int nb = wave * 2 + (it & 1), ks = it >> 1;
        gl_lds16(Bsrc + (size_t)(nb * 32 + l31) * 512 + ks * 16 + l5,
                 Bp + nb * 1024 + ks * 512);
    }

    for (int p = 0; p < 16; ++p) {
        const int k0 = p * 32;
        __syncthreads();   // panel p landed (vmcnt drain); buf[(p+1)&1] free
        if (p < 15) {
            f16* nbuf = Bp + ((p + 1) & 1) * BP_HALF;
#pragma unroll
            for (int it = 0; it < 4; ++it) {
                int nb = wave * 2 + (it & 1), ks = it >> 1;
                gl_lds16(Bsrc + (size_t)(nb * 32 + l31) * 512 + k0 + 32 + ks * 16 + l5,
                         nbuf + nb * 1024 + ks * 512);
            }
        }
        const f16* cbuf = Bp + (p & 1) * BP_HALF;
#pragma unroll
        for (int dk = 0; dk < 32; dk += 16) {
            f16x8 af[2], bf[2];
#pragma unroll
            for (int mt = 0; mt < 2; ++mt)
                af[mt] = *(const f16x8*)(Sb + (size_t)(mt * 32 + l31) * SB_STRIDE + k0 + dk + l5);
#pragma unroll
            for (int nt = 0; nt < 2; ++nt)
                bf[nt] = *(const f16x8*)(cbuf + (wave * 2 + nt) * 1024 + (dk >> 4) * 512 + lane * 8);
#pragma unroll
            for (int mt = 0; mt < 2; ++mt)
#pragma unroll
                for (int nt = 0; nt < 2; ++nt)
                    acc[mt][nt] = __builtin_amdgcn_mfma_f32_32x32x16_f16(af[mt], bf[nt], acc[mt][nt], 0, 0, 0);
        }
    }
    __syncthreads();  // all waves done reading Sb/Bp -> caller may overwrite Sb
}

// C/D mapping 32x32: col=lane&31, row=(reg&3)+8*(reg>>2)+4*(lane>>5)
__device__ __forceinline__ void emit_to_S(f16* __restrict__ Sb, const f32x16 acc[2][2],
                                          int t, float scale)
{
    const int lane = t & 63;
    const int wn = (t >> 6) * 64;
#pragma unroll
    for (int mt = 0; mt < 2; ++mt)
#pragma unroll
        for (int nt = 0; nt < 2; ++nt) {
            int col = wn + nt * 32 + (lane & 31);
#pragma unroll
            for (int r = 0; r < 16; ++r) {
                int row = mt * 32 + (r & 3) + 8 * (r >> 2) + 4 * (lane >> 5);
                Sb[(size_t)row * SB_STRIDE + col] = (f16)(acc[mt][nt][r] * scale);
            }
        }
}

__global__ __launch_bounds__(512) void chain_f16(
    const f16* __restrict__ q16, const f16* __restrict__ k16,
    const f16* __restrict__ ck16, const f16* __restrict__ vt16,
    const f16* __restrict__ cvt16, float* __restrict__ out)
{
    extern __shared__ f16 smem[];
    f16* Sb = smem;                       // [64][SB_STRIDE]
    f16* Bp = smem + 64 * SB_STRIDE;      // 2 x BP_HALF
    const int t = threadIdx.x;
    const int bh = blockIdx.x >> 3;
    const int q0 = (blockIdx.x & 7) * 64;
    const size_t SB = 512 * 512;

    // stage Q[q0..q0+64) into Sbuf
    const f16* Q = q16 + bh * SB;
    for (int i = t; i < 4096; i += 512) {
        int row = i >> 6, c = (i & 63) * 8;
        *(int4*)(Sb + (size_t)row * SB_STRIDE + c) =
            *(const int4*)(Q + (size_t)(q0 + row) * 512 + c);
    }
    // stage_nt's loop-top sync covers Q-write -> Sb-read

    f32x16 acc[2][2];

    // S1 = Q @ K^T
    stage_nt(k16 + bh * SB, Sb, Bp, t, acc);
    emit_to_S(Sb, acc, t, 1.0f);

    // S2 = S1 @ CK^T * SCALE
    stage_nt(ck16 + bh * SB, Sb, Bp, t, acc);
    emit_to_S(Sb, acc, t, SCALE);
    __syncthreads();

    // softmax rows (wave w -> rows 8w..8w+8)
    {
        const int lane = t & 63;
        const int wave = t >> 6;
        for (int rr = 0; rr < 8; ++rr) {
            int r = wave * 8 + rr;
            f16x8 xv = *(const f16x8*)(Sb + (size_t)r * SB_STRIDE + lane * 8);
            float x[8];
            float mx = -1e30f;
#pragma unroll
            for (int j = 0; j < 8; ++j) { x[j] = (float)xv[j]; mx = fmaxf(mx, x[j]); }
#pragma unroll
            for (int o = 32; o > 0; o >>= 1) mx = fmaxf(mx, __shfl_xor(mx, o));
            float s = 0.f;
#pragma unroll
            for (int j = 0; j < 8; ++j) { x[j] = __expf(x[j] - mx); s += x[j]; }
#pragma unroll
            for (int o = 32; o > 0; o >>= 1) s += __shfl_xor(s, o);
            float inv = 1.0f / s;
            f16x8 ov;
#pragma unroll
            for (int j = 0; j < 8; ++j) ov[j] = (f16)(x[j] * inv);
            *(f16x8*)(Sb + (size_t)r * SB_STRIDE + lane * 8) = ov;
        }
    }
    // stage_nt's loop-top sync covers softmax-write -> Sb-read

    // C1 = P @ V   (Vt is [bh][d][s]: NT-ready)
    stage_nt(vt16 + bh * SB, Sb, Bp, t, acc);
    emit_to_S(Sb, acc, t, 1.0f);

    // OUT = C1 @ CV (CVt NT-ready), merge-heads store f32
    stage_nt(cvt16 + bh * SB, Sb, Bp, t, acc);
    {
        const int lane = t & 63;
        const int wn = (t >> 6) * 64;
        int b = bh >> 2, h = bh & 3;
#pragma unroll
        for (int mt = 0; mt < 2; ++mt)
#pragma unroll
            for (int nt = 0; nt < 2; ++nt) {
                int col = h * 512 + wn + nt * 32 + (lane & 31);
#pragma unroll
                for (int r = 0; r < 16; ++r) {
                    int row = q0 + mt * 32 + (r & 3) + 8 * (r >> 2) + 4 * (lane >> 5);
                    out[((size_t)b * 512 + row) * 2048 + col] = acc[mt][nt][r];
                }
            }
    }
}

// ---------------------------------------------------------------- host
extern "C" void kernel_launch(void* const* d_in, const int* in_sizes, int n_in,
                              void* d_out, int out_size, void* d_ws, size_t ws_size,
                              hipStream_t stream)
{
    const float* hs = (const float*)d_in[0];
    const float* Wf[5] = {(const float*)d_in[1], (const float*)d_in[3],
                          (const float*)d_in[5], (const float*)d_in[7],
                          (const float*)d_in[9]};
    const float* bf[5] = {(const float*)d_in[2], (const float*)d_in[4],
                          (const float*)d_in[6], (const float*)d_in[8],
                          (const float*)d_in[10]};
    float* out = (float*)d_out;

    hipFuncSetAttribute((const void*)chain_f16,
                        hipFuncAttributeMaxDynamicSharedMemorySize, CHAIN_LDS);

    f16* ws = (f16*)d_ws;
    const size_t WELEM = 2048ULL * 2048;      // 4,194,304
    const size_t FULLACT = 64ULL * 512 * 512; // 16,777,216

    f16* W16[5];
    for (int i = 0; i < 5; ++i) W16[i] = ws + i * WELEM;
    f16* after_w = ws + 5 * WELEM;

    for (int i = 0; i < 5; ++i)
        conv_f32_f16<<<dim3(WELEM / 2048), 256, 0, stream>>>(Wf[i], W16[i], (int)WELEM);

    size_t full_need = (5 * WELEM + FULLACT + 5 * FULLACT) * sizeof(f16);  // 243,269,632
    if (ws_size >= full_need) {
        // ---------------- full path ----------------
        f16* hs16 = after_w;
        f16* act[5];
        for (int i = 0; i < 5; ++i) act[i] = after_w + FULLACT + i * FULLACT;

        conv_f32_f16<<<dim3(FULLACT / 2048), 256, 0, stream>>>(hs, hs16, (int)FULLACT);

        ProjPtrs P;
        for (int i = 0; i < 5; ++i) { P.W[i] = W16[i]; P.bias[i] = bf[i]; P.dst[i] = act[i]; }
        proj_f16<<<dim3(16, 64, 5), 256, 0, stream>>>(hs16, P);

        // act order: q,k,v^T,ck,cv^T -> chain(q,k,ck,vt,cvt)
        chain_f16<<<dim3(512), 512, CHAIN_LDS, stream>>>(
            act[0], act[1], act[3], act[2], act[4], out);
    } else {
        // ---------------- chunked path (54.5 MB ws) ----------------
        const size_t CHROW = 1048576ULL;      // 512*2048 elems per batch
        const size_t CHACT = 4ULL * 512 * 512;
        f16* hs16c = after_w;
        f16* act[5];
        for (int i = 0; i < 5; ++i) act[i] = after_w + CHROW + i * CHACT;

        ProjPtrs P;
        for (int i = 0; i < 5; ++i) { P.W[i] = W16[i]; P.bias[i] = bf[i]; P.dst[i] = act[i]; }

        for (int c = 0; c < 16; ++c) {
            conv_f32_f16<<<dim3(CHROW / 2048), 256, 0, stream>>>(
                hs + c * CHROW, hs16c, (int)CHROW);
            proj_f16<<<dim3(16, 4, 5), 256, 0, stream>>>(hs16c, P);
            chain_f16<<<dim3(32), 512, CHAIN_LDS, stream>>>(
                act[0], act[1], act[3], act[2], act[4], out + c * CHROW);
        }
    }

    (void)in_sizes; (void)n_in; (void)out_size;
}